// Round 10
// baseline (296.285 us; speedup 1.0000x reference)
//
#include <hip/hip_runtime.h>

// ---------------------------------------------------------------------------
// TripletLossWithHardMining  (B=4096, D=1024, fp32 in, fp32 scalar out)
//
//  K2 gemm_mask (R10): TALL-WAVE, BARRIER-FREE fused GEMM. Model (fits
//  R3-R9): LDS port is the binding constraint; B-LDS-reads scale with wave
//  cols x (block_rows/wave_rows) amplification. Fix:
//   - wave tile = 128 rows x 32 cols, BOTH mats (acc 128 AGPR as before).
//     B-reads/wave/window: 8 b128 (was 16, amp 2 -> 1).
//   - wave reads ONLY the 32 B-rows it staged itself -> no cross-wave LDS
//     sharing -> NO barriers at all; per-wave vmcnt discipline only.
//   - A direct global->VGPR (R6/R8-verified frag layout); all 4 waves load
//     identical A addresses -> L1 broadcast.
//   - 2-deep LDS dbuf (2 x (16+16) KB = 64 KB/block; 2 blocks/CU fit);
//     per window: vmcnt(8) [g2l(k)+A(k,h0) retired], prefetch g2l(k+1),
//     half0, reload A(h0), vmcnt(16) [A(k,h1) retired], half1, reload A(h1).
//     Buffer reuse safe: a wave's ds_reads of buf b retire before it issues
//     g2l(k+2,b) (MFMA operand lgkm waits force it); no inter-wave sharing.
//  Epilogue in squared-distance domain; atomicMax/Min on uint bits.
//
//  Dead-ends: R4 (dup traffic), R6 (unfused), R7 (reg cliff), R8 (JIT B),
//  R9 (barrier pipeline, LDS still 2x). R5 = 96.5us reference.
// ---------------------------------------------------------------------------

#define NB 4096
#define DIM 1024
#define EPSF 1e-6f
#define D_EPS2 (1024.0f * 1e-6f * 1e-6f)

#define BM 128           // block tile (rows and cols)
#define BK 64            // k-tile -> 16 windows

typedef __bf16  bf16x8 __attribute__((ext_vector_type(8)));
typedef float   f32x4  __attribute__((ext_vector_type(4)));

__device__ __forceinline__ unsigned short f2bf(float x) {
    unsigned u = __float_as_uint(x);
    u += 0x7FFFu + ((u >> 16) & 1u);   // round-to-nearest-even
    return (unsigned short)(u >> 16);
}

// async 16B/lane global->LDS; lds base wave-uniform, data lands at base+lane*16
__device__ __forceinline__ void g2l16(const unsigned short* g, unsigned short* l) {
    __builtin_amdgcn_global_load_lds(
        (const __attribute__((address_space(1))) unsigned int*)g,
        (__attribute__((address_space(3))) unsigned int*)l, 16, 0, 0);
}

#define FENCE    asm volatile("" ::: "memory")
#define VM8      asm volatile("s_waitcnt vmcnt(8)" ::: "memory")
#define VM16     asm volatile("s_waitcnt vmcnt(16)" ::: "memory")
#define VM0      asm volatile("s_waitcnt vmcnt(0)" ::: "memory")

// stats layout (NB-float slots):
// 0: base_a[i]  1: cn[j]  2: cp[j]  3: d_ap  4: d_an_row
// 5: hard_n bits (sq)  6: hard_p bits (sq)

__global__ __launch_bounds__(256) void row_stats_kernel(
    const float* __restrict__ a, const float* __restrict__ p,
    const float* __restrict__ n,
    unsigned short* __restrict__ abf, unsigned short* __restrict__ pbf,
    unsigned short* __restrict__ nbf, float* __restrict__ stats)
{
    const int t    = threadIdx.x;
    const int wave = t >> 6, lane = t & 63;
    const int row  = blockIdx.x * 4 + wave;
    const size_t base = (size_t)row * DIM;

    const float4* a4 = (const float4*)(a + base);
    const float4* p4 = (const float4*)(p + base);
    const float4* n4 = (const float4*)(n + base);

    float v[8] = {0,0,0,0,0,0,0,0};   // sa qa sp qp sn qn dap2 dan2
#pragma unroll
    for (int c = 0; c < 4; c++) {
        const int idx = c * 64 + lane;
        const float4 va = a4[idx];
        const float4 vp = p4[idx];
        const float4 vn = n4[idx];
        const float fa[4] = {va.x, va.y, va.z, va.w};
        const float fp[4] = {vp.x, vp.y, vp.z, vp.w};
        const float fn[4] = {vn.x, vn.y, vn.z, vn.w};
#pragma unroll
        for (int e = 0; e < 4; e++) {
            v[0] += fa[e];           v[1] += fa[e] * fa[e];
            v[2] += fp[e];           v[3] += fp[e] * fp[e];
            v[4] += fn[e];           v[5] += fn[e] * fn[e];
            float dp = fa[e] - fp[e] + EPSF;  v[6] += dp * dp;
            float dn = fa[e] - fn[e] + EPSF;  v[7] += dn * dn;
        }
        ushort4 ba, bp, bn;
        ba.x = f2bf(fa[0]); ba.y = f2bf(fa[1]); ba.z = f2bf(fa[2]); ba.w = f2bf(fa[3]);
        bp.x = f2bf(fp[0]); bp.y = f2bf(fp[1]); bp.z = f2bf(fp[2]); bp.w = f2bf(fp[3]);
        bn.x = f2bf(fn[0]); bn.y = f2bf(fn[1]); bn.z = f2bf(fn[2]); bn.w = f2bf(fn[3]);
        ((ushort4*)(abf + base))[idx] = ba;
        ((ushort4*)(pbf + base))[idx] = bp;
        ((ushort4*)(nbf + base))[idx] = bn;
    }

#pragma unroll
    for (int m = 32; m >= 1; m >>= 1)
#pragma unroll
        for (int q = 0; q < 8; q++) v[q] += __shfl_xor(v[q], m);

    if (lane == 0) {
        stats[0 * NB + row] = v[1] + 2.0f * EPSF * v[0] + D_EPS2;  // base_a
        stats[1 * NB + row] = v[5] - 2.0f * EPSF * v[4];           // cn
        stats[2 * NB + row] = v[3] - 2.0f * EPSF * v[2];           // cp
        stats[3 * NB + row] = sqrtf(v[6]);                         // d_ap
        stats[4 * NB + row] = sqrtf(v[7]);                         // d_an_row
        ((unsigned*)stats)[5 * NB + row] = 0u;                     // hard_n
        ((unsigned*)stats)[6 * NB + row] = 0x7f800000u;            // hard_p
    }
}

// grid (32, 32). XCD-banded swizzle: id%8 = XCD owns j-band of 4 tiles.
__global__ __launch_bounds__(256, 2) void gemm_mask_kernel(
    const unsigned short* __restrict__ Abf,
    const unsigned short* __restrict__ Nbf,
    const unsigned short* __restrict__ Pbf,
    float* __restrict__ stats)
{
    const int id = blockIdx.y * 32 + blockIdx.x;
    const int xc = id & 7, rr = id >> 3;
    const int j0 = (xc * 4 + (rr & 3)) * BM;
    const int i0 = (rr >> 2) * BM;

    __shared__ unsigned short sN[2][BM * BK];   // 2 x 16 KB
    __shared__ unsigned short sP[2][BM * BK];   // 2 x 16 KB -> 64 KB total

    const int t    = threadIdx.x;
    const int wave = t >> 6, lane = t & 63;
    const int quad = lane >> 4, lrow = lane & 15;

    // ---- staging: wave stages N/P rows [wave*32, +32) (the SAME rows it
    // will read). 8 rows per g2l (srow=lane>>3), 4 g2l per mat per window.
    // slot s = lane&7 of row r holds logical 16B chunk s ^ (r&7).
    const int srow = lane >> 3;
    const int kch  = ((lane & 7) ^ srow) * 8;
    const unsigned short* gN = Nbf + (size_t)(j0 + wave * 32 + srow) * DIM + kch;
    const unsigned short* gP = Pbf + (size_t)(j0 + wave * 32 + srow) * DIM + kch;
    const int lb = (wave * 32) * BK;

    // ---- A direct global->VGPR: frag row = lane&15 (tile im: +im*16),
    // k-subchunk = quad*8. Identical addresses across all 4 waves -> L1.
    const unsigned short* gA = Abf + (size_t)(i0 + lrow) * DIM + (quad << 3);

    // ---- B frag read: wave's cols = rows [wave*32,+32) of sN/sP.
    // logical chunk c = half*4+quad, physical c ^ (lrow&7) (row&7 == lrow&7).
    const int rsw0 = ((0 + quad) ^ (lrow & 7)) * 8;
    const int rsw1 = ((4 + quad) ^ (lrow & 7)) * 8;
    const int pboff = (wave * 32 + lrow) * BK;

    bf16x8 afr0[8], afr1[8];   // 64 VGPR: A frags for halves 0/1, 8 row-tiles
    f32x4 accN[8][2], accP[8][2];
#pragma unroll
    for (int im = 0; im < 8; im++)
#pragma unroll
        for (int jn = 0; jn < 2; jn++) {
            accN[im][jn] = (f32x4)(0.0f);
            accP[im][jn] = (f32x4)(0.0f);
        }

#define ISSUE_B(kw_, b_) do {                                                 \
    const unsigned short* _gn = gN + (size_t)(kw_) * BK;                      \
    const unsigned short* _gp = gP + (size_t)(kw_) * BK;                      \
    unsigned short* _ln = &sN[(b_)][lb];                                      \
    unsigned short* _lp = &sP[(b_)][lb];                                      \
    _Pragma("unroll")                                                         \
    for (int g = 0; g < 4; g++) {                                             \
        g2l16(_gn + (size_t)g * 8 * DIM, _ln + g * 8 * BK);                   \
        g2l16(_gp + (size_t)g * 8 * DIM, _lp + g * 8 * BK);                   \
    }                                                                         \
} while (0)

#define ISSUE_A(kw_, h_, arr_) do {                                           \
    const unsigned short* _ga = gA + (size_t)(kw_) * BK + (h_) * 32;          \
    _Pragma("unroll")                                                         \
    for (int im = 0; im < 8; im++)                                            \
        arr_[im] = *(const bf16x8*)(_ga + im * 16 * DIM);                     \
} while (0)

#define HALF(b_, rsw_, arr_) do {                                             \
    bf16x8 bnfr[2], bpfr[2];                                                  \
    _Pragma("unroll")                                                         \
    for (int jn = 0; jn < 2; jn++) {                                          \
        bnfr[jn] = *(const bf16x8*)(&sN[(b_)][pboff + jn * 16 * BK + (rsw_)]);\
        bpfr[jn] = *(const bf16x8*)(&sP[(b_)][pboff + jn * 16 * BK + (rsw_)]);\
    }                                                                         \
    _Pragma("unroll")                                                         \
    for (int im = 0; im < 8; im++)                                            \
        _Pragma("unroll")                                                     \
        for (int jn = 0; jn < 2; jn++) {                                      \
            accN[im][jn] = __builtin_amdgcn_mfma_f32_16x16x32_bf16(           \
                arr_[im], bnfr[jn], accN[im][jn], 0, 0, 0);                   \
            accP[im][jn] = __builtin_amdgcn_mfma_f32_16x16x32_bf16(           \
                arr_[im], bpfr[jn], accP[im][jn], 0, 0, 0);                   \
        }                                                                     \
} while (0)

// window k (buffer b): entry queue = [g2l(k):8][A(k,h0):8][A(k,h1):8]
#define WINDOW(k_, b_) do {                                                   \
    VM8;                             /* g2l(k)+A(k,h0) retired */             \
    ISSUE_B((k_) + 1, (b_) ^ 1); FENCE;                                       \
    HALF((b_), rsw0, afr0);                                                   \
    ISSUE_A((k_) + 1, 0, afr0); FENCE;                                        \
    VM16;                            /* A(k,h1) retired */                    \
    HALF((b_), rsw1, afr1);                                                   \
    ISSUE_A((k_) + 1, 1, afr1); FENCE;                                        \
} while (0)

    // prologue: queue = [g2l(0):8][A(0,h0):8][A(0,h1):8]
    ISSUE_B(0, 0); FENCE;
    ISSUE_A(0, 0, afr0); FENCE;
    ISSUE_A(0, 1, afr1); FENCE;

    for (int kp = 0; kp < 7; kp++) {     // windows 0..13
        WINDOW(2 * kp,     0);
        WINDOW(2 * kp + 1, 1);
    }
    WINDOW(14, 0);                       // window 14 (prefetches 15 -> buf1)
    // peeled window 15 (buf 1): no prefetch
    VM8;                                 // g2l(15)+A(15,h0) retired
    HALF(1, rsw0, afr0);
    VM0;                                 // A(15,h1) retired
    HALF(1, rsw1, afr1);

#undef WINDOW
#undef HALF
#undef ISSUE_A
#undef ISSUE_B

    // epilogue (SQUARED domain): sq = base_a[i] + c[j] - 2*dot
    const float* __restrict__ base_a = stats + 0 * NB;
    const float* __restrict__ cn_v   = stats + 1 * NB;
    const float* __restrict__ cp_v   = stats + 2 * NB;
    const float* __restrict__ d_ap   = stats + 3 * NB;
    const float* __restrict__ d_an   = stats + 4 * NB;
    unsigned* __restrict__ hard_n = ((unsigned*)stats) + 5 * NB;
    unsigned* __restrict__ hard_p = ((unsigned*)stats) + 6 * NB;

#pragma unroll
    for (int im = 0; im < 8; im++) {
#pragma unroll
        for (int r = 0; r < 4; r++) {
            const int gi = i0 + im * 16 + quad * 4 + r;
            const float cutN = d_ap[gi];
            const float cutP = d_an[gi];
            const float cutN2 = cutN * cutN;
            const float cutP2 = cutP * cutP;
            const float bi    = base_a[gi];
            float bestN = 0.0f;
            float bestP = __uint_as_float(0x7f800000u);
#pragma unroll
            for (int jn = 0; jn < 2; jn++) {
                const int gj = j0 + wave * 32 + jn * 16 + lrow;
                const float sqN = fmaxf(bi + cn_v[gj] - 2.0f * accN[im][jn][r], 0.0f);
                const float sqP = fmaxf(bi + cp_v[gj] - 2.0f * accP[im][jn][r], 0.0f);
                if (sqN < cutN2 && sqN > bestN) bestN = sqN;
                if (sqP > cutP2 && sqP < bestP) bestP = sqP;
            }
#pragma unroll
            for (int m = 1; m < 16; m <<= 1) {
                bestN = fmaxf(bestN, __shfl_xor(bestN, m));
                bestP = fminf(bestP, __shfl_xor(bestP, m));
            }
            if (lrow == 0) {
                const unsigned bn_ = __float_as_uint(bestN);
                const unsigned bp_ = __float_as_uint(bestP);
                if (bn_ != 0u)          atomicMax(hard_n + gi, bn_);
                if (bp_ != 0x7f800000u) atomicMin(hard_p + gi, bp_);
            }
        }
    }
}

__global__ __launch_bounds__(1024) void finalize_kernel(
    const float* __restrict__ stats, float* __restrict__ out)
{
    const unsigned* hard_n = ((const unsigned*)stats) + 5 * NB;
    const unsigned* hard_p = ((const unsigned*)stats) + 6 * NB;
    const float*    d_ap   = stats + 3 * NB;
    const int t = threadIdx.x;
    const int wave = t >> 6, lane = t & 63;
    __shared__ float pn[16], pp[16];
    __shared__ float s_dan, s_dpp;

    float sn = 0.0f, sp = 0.0f;
    for (int i = t; i < NB; i += 1024) {
        sn += sqrtf(__uint_as_float(hard_n[i]));          // sq -> dist (0 -> 0)
        const unsigned hp = hard_p[i];
        if (hp != 0x7f800000u) sp += sqrtf(__uint_as_float(hp));
    }
#pragma unroll
    for (int m = 32; m >= 1; m >>= 1) {
        sn += __shfl_xor(sn, m);
        sp += __shfl_xor(sp, m);
    }
    if (lane == 0) { pn[wave] = sn; pp[wave] = sp; }
    __syncthreads();
    if (t == 0) {
        float an = 0.0f, ap = 0.0f;
#pragma unroll
        for (int w = 0; w < 16; w++) { an += pn[w]; ap += pp[w]; }
        s_dan = an / (float)NB;
        s_dpp = ap / (float)NB;
    }
    __syncthreads();
    const float dan = s_dan, dpp = s_dpp;

    float accv = 0.0f;
    for (int i = t; i < NB; i += 1024)
        accv += fmaxf(d_ap[i] - 0.5f * dpp - 0.5f * dan + 1.0f, 0.0f);
#pragma unroll
    for (int m = 32; m >= 1; m >>= 1) accv += __shfl_xor(accv, m);
    if (lane == 0) pn[wave] = accv;
    __syncthreads();
    if (t == 0) {
        float s = 0.0f;
#pragma unroll
        for (int w = 0; w < 16; w++) s += pn[w];
        out[0] = s / (float)NB;
    }
}

extern "C" void kernel_launch(void* const* d_in, const int* in_sizes, int n_in,
                              void* d_out, int out_size, void* d_ws, size_t ws_size,
                              hipStream_t stream) {
    const float* a = (const float*)d_in[0];
    const float* p = (const float*)d_in[1];
    const float* n = (const float*)d_in[2];
    float* out = (float*)d_out;

    // ws layout: abf | pbf | nbf | stats(7*NB floats)  => ~25.3 MB
    unsigned short* abf = (unsigned short*)d_ws;
    unsigned short* pbf = abf + (size_t)NB * DIM;
    unsigned short* nbf = pbf + (size_t)NB * DIM;
    float* stats = (float*)(nbf + (size_t)NB * DIM);

    row_stats_kernel<<<NB / 4, 256, 0, stream>>>(a, p, n, abf, pbf, nbf, stats);

    dim3 grid(NB / BM, NB / BM);
    gemm_mask_kernel<<<grid, 256, 0, stream>>>(abf, nbf, pbf, stats);

    finalize_kernel<<<1, 1024, 0, stream>>>(stats, out);
}